// Round 6
// baseline (320.661 us; speedup 1.0000x reference)
//
#include <hip/hip_runtime.h>

typedef _Float16 f16;
typedef _Float16 f16x8 __attribute__((ext_vector_type(8)));
typedef float f32x4 __attribute__((ext_vector_type(4)));

#define CDIM 256
#define NPIX 9216
#define NB 8

__device__ __forceinline__ f32x4 mfma16(f16x8 a, f16x8 b, f32x4 c) {
  return __builtin_amdgcn_mfma_f32_16x16x32_f16(a, b, c, 0, 0, 0);
}
__device__ __forceinline__ f16x8 ld8(const f16* p) { return *(const f16x8*)p; }

__device__ __forceinline__ void stage16(const void* g, void* l) {
  __builtin_amdgcn_global_load_lds((const __attribute__((address_space(1))) unsigned int*)g,
                                   (__attribute__((address_space(3))) unsigned int*)l, 16, 0, 0);
}
#define S_BARRIER() do { asm volatile("" ::: "memory"); __builtin_amdgcn_s_barrier(); asm volatile("" ::: "memory"); } while (0)
#define WAIT_VM(N) do { asm volatile("s_waitcnt vmcnt(" #N ")" ::: "memory"); __builtin_amdgcn_sched_barrier(0); } while (0)
#define WAIT_LGKM0() do { asm volatile("s_waitcnt lgkmcnt(0)" ::: "memory"); __builtin_amdgcn_sched_barrier(0); } while (0)

// Fragment layout convention ("lane-linear"): a 1KB frag holds a 16(row)x32(k)
// f16 tile; lane (l15=row, q) element k=8q+e lives at byte lane*16 + e*2
// (= q*256 + l15*16 + e*2). LDS read = base + lane*16 -> conflict-free, and
// global_load_lds staging is plain linear.

// ---------------- K1: fold weights; WqF in frag layout ----------------
__global__ void prep_weights(const float* __restrict__ Wq,
                             const float* __restrict__ Wk, const float* __restrict__ bk,
                             const float* __restrict__ Wv, const float* __restrict__ bv,
                             const float* __restrict__ Ws, const float* __restrict__ bs,
                             f16* __restrict__ WqF, f16* __restrict__ Wk2H, f16* __restrict__ Wv2H,
                             float* __restrict__ bk2, float* __restrict__ bv2) {
  int o = blockIdx.x, c = threadIdx.x;
  float ak = 0.f, av = 0.f;
  for (int i = 0; i < CDIM; ++i) {
    float w = Ws[o*CDIM + i];
    ak += w * Wk[i*CDIM + c];
    av += w * Wv[i*CDIM + c];
  }
  Wk2H[o*CDIM + c] = (f16)ak;
  Wv2H[o*CDIM + c] = (f16)av;
  {
    int f = o >> 4, ksw = c >> 5, qf_ = (c >> 3) & 3, e = c & 7;
    size_t byte = (size_t)(f*8 + ksw)*1024 + (size_t)qf_*256 + (size_t)(o & 15)*16 + e*2;
    *(f16*)((char*)WqF + byte) = (f16)Wq[o*CDIM + c];
  }
  if (c == 0) {
    float sk = 0.f, sv = 0.f;
    for (int i = 0; i < CDIM; ++i) { float w = Ws[o*CDIM + i]; sk += w*bk[i]; sv += w*bv[i]; }
    bk2[o] = sk + bs[o];
    bv2[o] = sv + bs[o];
  }
}

// ---------------- K2: x[b][c][n] f32 -> xT swizzled [b][n][c] f16 ----------------
// row n = 512B; 16B unit u (= c>>3) stored at u ^ (n&7).
__global__ void transpose_x(const float* __restrict__ x, char* __restrict__ xT) {
  __shared__ f16 tile[32][34];   // [c][n]
  int c0 = blockIdx.x * 32, n0 = blockIdx.y * 32, b = blockIdx.z;
  int tx = threadIdx.x, ty = threadIdx.y;
#pragma unroll
  for (int j = 0; j < 4; ++j) {
    int cl = ty + 8*j;
    tile[cl][tx] = (f16)x[(size_t)(b*CDIM + c0 + cl)*NPIX + n0 + tx];
  }
  __syncthreads();
  int tid = ty*32 + tx;
  if (tid < 128) {
    int nl = tid >> 2, u = tid & 3;
    int n = n0 + nl;
    int cu = (c0 >> 3) + u;
    f16x8 v;
#pragma unroll
    for (int e = 0; e < 8; ++e) v[e] = tile[8*u + e][nl];
    size_t byte = (size_t)(b*NPIX + n)*512 + (size_t)((cu ^ (n & 7)) << 4);
    *(f16x8*)(xT + byte) = v;
  }
}

// ---------------- K3: K/V at subsampled pixels -> frag-linear chunk layouts ----------------
// kB: per (b,ch): 16KB = frag(ks,kt): K[m=32ch+16kt+l15][k=32ks+8q+e]
// vB: per (b,ch): 16KB = frag(ct):    V[m=32ch+8q+e][c=16ct+l15]
__global__ __launch_bounds__(256) void compute_kv(
    const char* __restrict__ xT, const f16* __restrict__ Wk2H, const f16* __restrict__ Wv2H,
    const float* __restrict__ bk2, const float* __restrict__ bv2,
    char* __restrict__ kB, char* __restrict__ vB) {
  int ch = blockIdx.x;            // key chunk (32 keys)
  int m0 = ch * 32;
  int b = blockIdx.y;
  int tid = threadIdx.x;
  int w = tid >> 6, lane = tid & 63, l15 = lane & 15, q = lane >> 4;
  size_t chbase = (size_t)(b*32 + ch)*16384;

  const char* xrow[2]; int xn7[2];
#pragma unroll
  for (int mt2 = 0; mt2 < 2; ++mt2) {
    int m = m0 + 16*mt2 + l15;
    int n = 288*(m >> 5) + 3*(m & 31);   // subsampled pixel index
    xrow[mt2] = xT + (size_t)(b*NPIX + n)*512;
    xn7[mt2] = n & 7;
  }
  const f16 *kwb[4], *vwb[4];
#pragma unroll
  for (int t = 0; t < 4; ++t) {
    kwb[t] = Wk2H + (size_t)(64*w + 16*t + l15)*CDIM + 8*q;
    vwb[t] = Wv2H + (size_t)(64*w + 16*t + l15)*CDIM + 8*q;
  }
  f32x4 accK[2][4] = {};
  f32x4 accV[4][2] = {};
  for (int ks = 0; ks < 8; ++ks) {
    f16x8 am[2], wk[4], wv[4];
#pragma unroll
    for (int mt2 = 0; mt2 < 2; ++mt2)
      am[mt2] = *(const f16x8*)(xrow[mt2] + (((q + 4*ks) ^ xn7[mt2]) << 4));
#pragma unroll
    for (int t = 0; t < 4; ++t) { wk[t] = ld8(kwb[t] + 32*ks); wv[t] = ld8(vwb[t] + 32*ks); }
#pragma unroll
    for (int mt2 = 0; mt2 < 2; ++mt2)
#pragma unroll
      for (int ot = 0; ot < 4; ++ot) {
        accK[mt2][ot] = mfma16(am[mt2], wk[ot], accK[mt2][ot]);   // D[m][o]
        accV[ot][mt2] = mfma16(wv[ot], am[mt2], accV[ot][mt2]);   // D[c][m]
      }
  }
  // K writes: D[m=m0+16mt2+4q+r][cin=64w+16ot+l15]
#pragma unroll
  for (int mt2 = 0; mt2 < 2; ++mt2)
#pragma unroll
    for (int ot = 0; ot < 4; ++ot) {
      int cin = 64*w + 16*ot + l15;
      float bo = bk2[cin];
      int ks_t = (64*w + 16*ot) >> 5;
      int qf_t = ((ot & 1) << 1) | (l15 >> 3);
#pragma unroll
      for (int r = 0; r < 4; ++r) {
        size_t byte = chbase + (size_t)(2*ks_t + mt2)*1024 + (size_t)qf_t*256 + (4*q + r)*16 + (l15 & 7)*2;
        *(f16*)(kB + byte) = (f16)(accK[mt2][ot][r] + bo);
      }
    }
  // V writes: D[c=64w+16ct+4q+r][m=m0+16mt2+l15]
#pragma unroll
  for (int ct = 0; ct < 4; ++ct) {
    f32x4 bv4 = *(const f32x4*)(bv2 + 64*w + 16*ct + 4*q);
#pragma unroll
    for (int mt2 = 0; mt2 < 2; ++mt2) {
      int qf_t = 2*mt2 + (l15 >> 3);
#pragma unroll
      for (int r = 0; r < 4; ++r) {
        size_t byte = chbase + (size_t)(4*w + ct)*1024 + (size_t)qf_t*256 + (4*q + r)*16 + (l15 & 7)*2;
        *(f16*)(vB + byte) = (f16)(accV[ct][mt2][r] + bv4[r]);
      }
    }
  }
}

// ---------------- K4: flash attention, 64 q-rows, 32-key chunks ----------------
// 512 thr = 8 waves: w = rt*2+kt (rt: 16-row group, kt: key-half / c-half)
// LDS (70KB): pairK[2]@0/16K, pairV[2]@32K/48K, P@64K(4KB), stats@68K(1KB)
__global__ __launch_bounds__(512, 4) void attention(
    const char* __restrict__ xT, const f16* __restrict__ WqF, const float* __restrict__ bq,
    const char* __restrict__ kB, const char* __restrict__ vB,
    const float* __restrict__ x, const float* __restrict__ gamma_p,
    float* __restrict__ out) {
  __shared__ char lds[70656];

  int bid = blockIdx.x;
  int b = bid & 7;                 // XCD-bijective: 1152 = 8*144
  int ntb = bid >> 3;
  int n0 = ntb * 64;
  int tid = threadIdx.x;
  int w = tid >> 6, lane = tid & 63, l15 = lane & 15, q = lane >> 4;
  int rt = w >> 1, kt = w & 1;

  const char* kBb = kB + (size_t)(b*32)*16384;
  const char* vBb = vB + (size_t)(b*32)*16384;
  char* Pb = lds + 65536;
  float* st0 = (float*)(lds + 69632);
  float* st1 = (float*)(lds + 69632 + 512);

  // ---- prologue: stage xT tile (32KB) into lds[0..32K) ----
  {
    const char* xTt = xT + (size_t)(b*NPIX + n0)*512;
    int so = tid*16;
    stage16(xTt + so,          lds + so);
    stage16(xTt + so +  8192,  lds + so +  8192);
    stage16(xTt + so + 16384,  lds + so + 16384);
    stage16(xTt + so + 24576,  lds + so + 24576);
  }
  float bo0 = bq[32*w + l15], bo1 = bq[32*w + 16 + l15];
  f16x8 wb[2][8];
  {
    const char* base = (const char*)WqF + (size_t)(2*w)*8192 + (size_t)lane*16;
#pragma unroll
    for (int ot = 0; ot < 2; ++ot)
#pragma unroll
      for (int ks = 0; ks < 8; ++ks)
        wb[ot][ks] = *(const f16x8*)(base + (ot*8 + ks)*1024);
  }
  WAIT_VM(0);
  S_BARRIER();

  // ---- Phase A: q = x.Wq^T + bq; wave w computes o-slice [32w,32w+32) for all 64 rows ----
  {
    f32x4 acc[4][2] = {};
#pragma unroll
    for (int ks = 0; ks < 8; ++ks)
#pragma unroll
      for (int nt = 0; nt < 4; ++nt) {
        int n = 16*nt + l15;
        f16x8 a = *(const f16x8*)(lds + n*512 + (((q + 4*ks) ^ (n & 7)) << 4));
        acc[nt][0] = mfma16(a, wb[0][ks], acc[nt][0]);
        acc[nt][1] = mfma16(a, wb[1][ks], acc[nt][1]);
      }
    // write q-frags (frag index nt*8 + w, since o-slice 32w == k-range of frag w)
#pragma unroll
    for (int nt = 0; nt < 4; ++nt)
#pragma unroll
      for (int ot = 0; ot < 2; ++ot) {
        float bo = ot ? bo1 : bo0;
#pragma unroll
        for (int r = 0; r < 4; ++r) {
          size_t byte = 32768 + (size_t)(nt*8 + w)*1024 + (size_t)(2*ot + (l15 >> 3))*256 + (4*q + r)*16 + (l15 & 7)*2;
          *(f16*)(lds + byte) = (f16)(acc[nt][ot][r] + bo);
        }
      }
  }
  WAIT_LGKM0();
  S_BARRIER();

  // ---- read my Q A-frags (rows 16rt..16rt+16, all k) ----
  f16x8 qf[8];
#pragma unroll
  for (int ks = 0; ks < 8; ++ks)
    qf[ks] = *(const f16x8*)(lds + 32768 + (size_t)(rt*8 + ks)*1024 + lane*16);
  WAIT_LGKM0();
  S_BARRIER();     // all q reads done; pairK/pairV areas free

  // ---- stage K0,V0,K1,V1 ----
  {
    int so = tid*16;
    stage16(kBb + so,         lds + so);          stage16(kBb + so + 8192,         lds + so + 8192);
    stage16(vBb + so,         lds + 32768 + so);  stage16(vBb + so + 8192,         lds + 32768 + so + 8192);
    stage16(kBb + 16384 + so, lds + 16384 + so);  stage16(kBb + 16384 + so + 8192, lds + 16384 + so + 8192);
    stage16(vBb + 16384 + so, lds + 49152 + so);  stage16(vBb + 16384 + so + 8192, lds + 49152 + so + 8192);
  }
  WAIT_VM(4);      // K0,V0 resident; K1,V1 in flight
  S_BARRIER();

  // ---- main loop over 32 key-chunks ----
  f32x4 o_[8];
#pragma unroll
  for (int i = 0; i < 8; ++i) o_[i] = (f32x4){0.f, 0.f, 0.f, 0.f};
  f32x4 m4 = {-3e38f, -3e38f, -3e38f, -3e38f};
  f32x4 l4 = {0.f, 0.f, 0.f, 0.f};

#pragma unroll 2
  for (int ch = 0; ch < 32; ++ch) {
    const int pb = ch & 1;
    const char* kc = lds + pb*16384;
    const char* vc = lds + 32768 + pb*16384;

    // 1. S = q . K^T  (16 rows x 16 keys per wave)
    f32x4 S_ = {0.f, 0.f, 0.f, 0.f};
#pragma unroll
    for (int ks = 0; ks < 8; ++ks) {
      f16x8 kf = *(const f16x8*)(kc + (ks*2 + kt)*1024 + lane*16);
      S_ = mfma16(qf[ks], kf, S_);
    }
    // 2. row-max over the 16 keys (reduce over l15)
    f32x4 mx = S_;
#pragma unroll
    for (int d = 1; d < 16; d <<= 1)
#pragma unroll
      for (int r = 0; r < 4; ++r) mx[r] = fmaxf(mx[r], __shfl_xor(mx[r], d));
    // 3. exchange with kt-partner
    if (l15 == 0) *(f32x4*)(st0 + w*16 + 4*q) = mx;
    WAIT_LGKM0();
    S_BARRIER();
    f32x4 pr = *(const f32x4*)(st0 + (w ^ 1)*16 + 4*q);
    f32x4 pm;
#pragma unroll
    for (int r = 0; r < 4; ++r) pm[r] = fmaxf(mx[r], pr[r]);
    int ok = 1;
#pragma unroll
    for (int r = 0; r < 4; ++r) ok &= (pm[r] <= m4[r] + 8.0f);
    if (!__all(ok)) {              // T13 defer-max: rescale only on real growth
      f32x4 al;
#pragma unroll
      for (int r = 0; r < 4; ++r) {
        float mn = fmaxf(m4[r], pm[r]);
        al[r] = __expf(m4[r] - mn);
        m4[r] = mn;
      }
#pragma unroll
      for (int i = 0; i < 8; ++i)
#pragma unroll
        for (int r = 0; r < 4; ++r) o_[i][r] *= al[r];
#pragma unroll
      for (int r = 0; r < 4; ++r) l4[r] *= al[r];
    }
    // 4. P = exp(S - m); row partial sum; write P frag
    f32x4 P_;
#pragma unroll
    for (int r = 0; r < 4; ++r) P_[r] = __expf(S_[r] - m4[r]);
    f32x4 ps = P_;
#pragma unroll
    for (int d = 1; d < 16; d <<= 1)
#pragma unroll
      for (int r = 0; r < 4; ++r) ps[r] += __shfl_xor(ps[r], d);
#pragma unroll
    for (int r = 0; r < 4; ++r) l4[r] += ps[r];
    {
      char* dst = Pb + rt*1024 + (size_t)(2*kt + (l15 >> 3))*256 + (l15 & 7)*2;
#pragma unroll
      for (int r = 0; r < 4; ++r)
        *(f16*)(dst + (4*q + r)*16) = (f16)P_[r];
    }
    WAIT_LGKM0();
    S_BARRIER();
    // 5. O += P . V (wave covers c-slice 128*kt)
    f16x8 pa = *(const f16x8*)(Pb + rt*1024 + lane*16);
#pragma unroll
    for (int i = 0; i < 8; ++i) {
      f16x8 vf = *(const f16x8*)(vc + (8*kt + i)*1024 + lane*16);
      o_[i] = mfma16(pa, vf, o_[i]);
    }
    // 6. rotate staging
    S_BARRIER();
    if (ch < 30) {
      const char* ksrc = kBb + (size_t)(ch + 2)*16384;
      const char* vsrc = vBb + (size_t)(ch + 2)*16384;
      char* kd = lds + pb*16384;
      char* vd = lds + 32768 + pb*16384;
      int so = tid*16;
      stage16(ksrc + so, kd + so); stage16(ksrc + so + 8192, kd + so + 8192);
      stage16(vsrc + so, vd + so); stage16(vsrc + so + 8192, vd + so + 8192);
      WAIT_VM(4);
    } else if (ch == 30) {
      WAIT_VM(0);
    }
    if (ch < 31) S_BARRIER();
  }

  // ---- epilogue: merge l across kt pair; out = gamma*O/l + x ----
  if (l15 == 0) *(f32x4*)(st1 + w*16 + 4*q) = l4;
  WAIT_LGKM0();
  S_BARRIER();
  f32x4 lp = *(const f32x4*)(st1 + (w ^ 1)*16 + 4*q);
  f32x4 inv;
#pragma unroll
  for (int r = 0; r < 4; ++r) inv[r] = 1.0f / (l4[r] + lp[r]);
  float g = gamma_p[0];
#pragma unroll
  for (int i = 0; i < 8; ++i) {
    int c = 128*kt + 16*i + l15;
    size_t base = (size_t)(b*CDIM + c)*NPIX + n0 + 16*rt + 4*q;
    f32x4 xv = *(const f32x4*)(x + base);
    f32x4 ov;
#pragma unroll
    for (int r = 0; r < 4; ++r) ov[r] = g * (o_[i][r] * inv[r]) + xv[r];
    *(f32x4*)(out + base) = ov;
  }
}

extern "C" void kernel_launch(void* const* d_in, const int* in_sizes, int n_in,
                              void* d_out, int out_size, void* d_ws, size_t ws_size,
                              hipStream_t stream) {
  (void)in_sizes; (void)n_in; (void)out_size; (void)ws_size;
  const float* x     = (const float*)d_in[0];
  const float* Wq    = (const float*)d_in[1];
  const float* bq    = (const float*)d_in[2];
  const float* Wk    = (const float*)d_in[3];
  const float* bk    = (const float*)d_in[4];
  const float* Wv    = (const float*)d_in[5];
  const float* bv    = (const float*)d_in[6];
  const float* Ws    = (const float*)d_in[7];
  const float* bs    = (const float*)d_in[8];
  const float* gamma = (const float*)d_in[9];

  char* ws = (char*)d_ws;
  float* bk2 = (float*)(ws);
  float* bv2 = (float*)(ws + 1024);
  char* xT   = ws + 4096;
  char* kB   = ws + 4096 + 37748736;
  char* vB   = kB + 4194304;
  f16* WqF   = (f16*)(vB + 4194304);
  f16* Wk2H  = WqF + 65536;
  f16* Wv2H  = Wk2H + 65536;

  prep_weights<<<256, 256, 0, stream>>>(Wq, Wk, bk, Wv, bv, Ws, bs, WqF, Wk2H, Wv2H, bk2, bv2);
  transpose_x<<<dim3(8, 288, 8), dim3(32, 8), 0, stream>>>(x, xT);
  compute_kv<<<dim3(32, 8), 256, 0, stream>>>(xT, Wk2H, Wv2H, bk2, bv2, kB, vB);
  attention<<<1152, 512, 0, stream>>>(xT, WqF, bq, kB, vB, x, gamma, (float*)d_out);
}

// Round 9
// 197.199 us; speedup vs baseline: 1.6261x; 1.6261x over previous
//
#include <hip/hip_runtime.h>

typedef _Float16 f16;
typedef _Float16 f16x8 __attribute__((ext_vector_type(8)));
typedef __fp16 fp16x2 __attribute__((ext_vector_type(2)));
typedef float f32x4 __attribute__((ext_vector_type(4)));
typedef float f32x16 __attribute__((ext_vector_type(16)));

#define CDIM 256
#define NPIX 9216
#define NB 8

__device__ __forceinline__ f32x4 mfma16(f16x8 a, f16x8 b, f32x4 c) {
  return __builtin_amdgcn_mfma_f32_16x16x32_f16(a, b, c, 0, 0, 0);
}
__device__ __forceinline__ f32x16 mfma32(f16x8 a, f16x8 b, f32x16 c) {
  return __builtin_amdgcn_mfma_f32_32x32x16_f16(a, b, c, 0, 0, 0);
}
__device__ __forceinline__ f16x8 ld8(const f16* p) { return *(const f16x8*)p; }

__device__ __forceinline__ void stage16(const void* g, void* l) {
  __builtin_amdgcn_global_load_lds((const __attribute__((address_space(1))) unsigned int*)g,
                                   (__attribute__((address_space(3))) unsigned int*)l, 16, 0, 0);
}
#define S_BARRIER() do { asm volatile("" ::: "memory"); __builtin_amdgcn_s_barrier(); asm volatile("" ::: "memory"); } while (0)
#define WAIT_VM(N) do { asm volatile("s_waitcnt vmcnt(" #N ")" ::: "memory"); __builtin_amdgcn_sched_barrier(0); } while (0)

__device__ __forceinline__ unsigned pkrtz(float a, float b) {
  union { fp16x2 h; unsigned u; } cv;
  cv.h = __builtin_amdgcn_cvt_pkrtz(a, b);
  return cv.u;
}
union U8 { f16x8 v; unsigned u[4]; };

// Pack 8 f32 (reg-order v0..v7 of a 32x32 D half-group) into the f16x8
// B-frag word order, exchanging halves with the lane^32 partner via shfl.
// Target per lane (l31, hh): elements e=0..7 = k-index 8hh+e of the group.
// Reg j holds k=(j&3)+8*(j>>2)+4hh -> locals give {0,1,2,3}+4hh and
// {8,9,10,11}+4hh; the partner supplies the other quads.
__device__ __forceinline__ f16x8 pack_swap(float v0, float v1, float v2, float v3,
                                           float v4, float v5, float v6, float v7,
                                           int hh) {
  unsigned a  = pkrtz(v0, v1);   // k {0,1}+4hh
  unsigned b2 = pkrtz(v2, v3);   // k {2,3}+4hh
  unsigned c2 = pkrtz(v4, v5);   // k {8,9}+4hh
  unsigned d2 = pkrtz(v6, v7);   // k {10,11}+4hh
  unsigned ex1 = __shfl_xor(hh ? a : c2, 32);  // hh=0 gets partner-a (k4,5); hh=1 gets partner-c2 (k8,9)
  unsigned ex2 = __shfl_xor(hh ? b2 : d2, 32); // hh=0 gets partner-b2 (k6,7); hh=1 gets partner-d2 (k10,11)
  U8 r;
  r.u[0] = hh ? ex1 : a;    // e0,e1 = k 8hh+0,1
  r.u[1] = hh ? ex2 : b2;   // e2,e3
  r.u[2] = hh ? c2 : ex1;   // e4,e5
  r.u[3] = hh ? d2 : ex2;   // e6,e7
  return r.v;
}

// Frag conventions (32x32x16): A: lane(l31,h) holds A[row=l31][k=8h+e].
// B: lane(l31,h) holds B[k=8h+e][col=l31]. Both are 1KB "lane-linear" frags
// (lane*16 bytes). D: col=lane&31, row=(reg&3)+8*(reg>>2)+4*(lane>>5).

// ---------------- K1: fold weights; WqF as 32x32-A frags ----------------
__global__ void prep_weights(const float* __restrict__ Wq,
                             const float* __restrict__ Wk, const float* __restrict__ bk,
                             const float* __restrict__ Wv, const float* __restrict__ bv,
                             const float* __restrict__ Ws, const float* __restrict__ bs,
                             f16* __restrict__ WqF, f16* __restrict__ Wk2H, f16* __restrict__ Wv2H,
                             float* __restrict__ bk2, float* __restrict__ bv2) {
  int o = blockIdx.x, c = threadIdx.x;
  float ak = 0.f, av = 0.f;
  for (int i = 0; i < CDIM; ++i) {
    float w = Ws[o*CDIM + i];
    ak += w * Wk[i*CDIM + c];
    av += w * Wv[i*CDIM + c];
  }
  Wk2H[o*CDIM + c] = (f16)ak;
  Wv2H[o*CDIM + c] = (f16)av;
  {
    size_t byte = (size_t)((o >> 5)*16 + (c >> 4))*1024
                + (size_t)(((c >> 3) & 1)*32 + (o & 31))*16 + (c & 7)*2;
    *(f16*)((char*)WqF + byte) = (f16)Wq[o*CDIM + c];
  }
  if (c == 0) {
    float sk = 0.f, sv = 0.f;
    for (int i = 0; i < CDIM; ++i) { float w = Ws[o*CDIM + i]; sk += w*bk[i]; sv += w*bv[i]; }
    bk2[o] = sk + bs[o];
    bv2[o] = sv + bs[o];
  }
}

// ---------------- K2: x[b][c][n] f32 -> xT swizzled [b][n][c] f16 ----------------
__global__ void transpose_x(const float* __restrict__ x, char* __restrict__ xT) {
  __shared__ f16 tile[32][34];   // [c][n]
  int c0 = blockIdx.x * 32, n0 = blockIdx.y * 32, b = blockIdx.z;
  int tx = threadIdx.x, ty = threadIdx.y;
#pragma unroll
  for (int j = 0; j < 4; ++j) {
    int cl = ty + 8*j;
    tile[cl][tx] = (f16)x[(size_t)(b*CDIM + c0 + cl)*NPIX + n0 + tx];
  }
  __syncthreads();
  int tid = ty*32 + tx;
  if (tid < 128) {
    int nl = tid >> 2, u = tid & 3;
    int n = n0 + nl;
    int cu = (c0 >> 3) + u;
    f16x8 v;
#pragma unroll
    for (int e = 0; e < 8; ++e) v[e] = tile[8*u + e][nl];
    size_t byte = (size_t)(b*NPIX + n)*512 + (size_t)((cu ^ (n & 7)) << 4);
    *(f16x8*)(xT + byte) = v;
  }
}

// ---------------- K3: K/V at subsampled pixels -> 32x32-frag-linear chunks ----------------
__global__ __launch_bounds__(256) void compute_kv(
    const char* __restrict__ xT, const f16* __restrict__ Wk2H, const f16* __restrict__ Wv2H,
    const float* __restrict__ bk2, const float* __restrict__ bv2,
    char* __restrict__ kB, char* __restrict__ vB) {
  int ch = blockIdx.x;            // key tile (32 keys)
  int m0 = ch * 32;
  int b = blockIdx.y;
  int tid = threadIdx.x;
  int w = tid >> 6, lane = tid & 63, l15 = lane & 15, q = lane >> 4;
  size_t chbase = (size_t)(b*32 + ch)*16384;

  const char* xrow[2]; int xn7[2];
#pragma unroll
  for (int mt2 = 0; mt2 < 2; ++mt2) {
    int m = m0 + 16*mt2 + l15;
    int n = 288*(m >> 5) + 3*(m & 31);   // subsampled pixel index
    xrow[mt2] = xT + (size_t)(b*NPIX + n)*512;
    xn7[mt2] = n & 7;
  }
  const f16 *kwb[4], *vwb[4];
#pragma unroll
  for (int t = 0; t < 4; ++t) {
    kwb[t] = Wk2H + (size_t)(64*w + 16*t + l15)*CDIM + 8*q;
    vwb[t] = Wv2H + (size_t)(64*w + 16*t + l15)*CDIM + 8*q;
  }
  f32x4 accK[2][4] = {};
  f32x4 accV[4][2] = {};
  for (int ks = 0; ks < 8; ++ks) {
    f16x8 am[2], wk[4], wv[4];
#pragma unroll
    for (int mt2 = 0; mt2 < 2; ++mt2)
      am[mt2] = *(const f16x8*)(xrow[mt2] + (((q + 4*ks) ^ xn7[mt2]) << 4));
#pragma unroll
    for (int t = 0; t < 4; ++t) { wk[t] = ld8(kwb[t] + 32*ks); wv[t] = ld8(vwb[t] + 32*ks); }
#pragma unroll
    for (int mt2 = 0; mt2 < 2; ++mt2)
#pragma unroll
      for (int ot = 0; ot < 4; ++ot) {
        accK[mt2][ot] = mfma16(am[mt2], wk[ot], accK[mt2][ot]);   // D[m][o]
        accV[ot][mt2] = mfma16(wv[ot], am[mt2], accV[ot][mt2]);   // D[c][m]
      }
  }
  // K writes: keyrel=16mt2+4q+r, cin=64w+16ot+l15
#pragma unroll
  for (int mt2 = 0; mt2 < 2; ++mt2)
#pragma unroll
    for (int ot = 0; ot < 4; ++ot) {
      int cin = 64*w + 16*ot + l15;
      float bo = bk2[cin];
      size_t fb = chbase + (size_t)(cin >> 4)*1024 + (size_t)(((cin >> 3) & 1)*32)*16 + (cin & 7)*2;
#pragma unroll
      for (int r = 0; r < 4; ++r) {
        int keyrel = 16*mt2 + 4*q + r;
        *(f16*)(kB + fb + (size_t)keyrel*16) = (f16)(accK[mt2][ot][r] + bo);
      }
    }
  // V writes: c=64w+16ct+4q+r, keyrel=16mt2+l15
#pragma unroll
  for (int ct = 0; ct < 4; ++ct) {
    f32x4 bv4 = *(const f32x4*)(bv2 + 64*w + 16*ct + 4*q);
#pragma unroll
    for (int mt2 = 0; mt2 < 2; ++mt2) {
#pragma unroll
      for (int r = 0; r < 4; ++r) {
        int c = 64*w + 16*ct + 4*q + r;
        size_t byte = chbase + (size_t)(2*(c >> 5) + mt2)*1024
                    + (size_t)((l15 >> 3)*32 + (c & 31))*16 + (l15 & 7)*2;
        *(f16*)(vB + byte) = (f16)(accV[ct][mt2][r] + bv4[r]);
      }
    }
  }
}

// ---------------- K4: attention, swapped-QK 32x32, lane-local softmax ----------------
__global__ __launch_bounds__(256, 2) void attention(
    const char* __restrict__ xT, const f16* __restrict__ WqF, const float* __restrict__ bq,
    const char* __restrict__ kB, const char* __restrict__ vB,
    const float* __restrict__ xg, const float* __restrict__ gamma_p,
    float* __restrict__ out) {
  __shared__ char lds[65536];    // [2][ K 16KB | V 16KB ]

  int bid = blockIdx.x;
  int b = bid & 7;               // XCD-bijective: 576 = 8*72
  int tile = bid >> 3;
  int tid = threadIdx.x;
  int w = tid >> 6, lane = tid & 63, l31 = lane & 31, hh = lane >> 5;
  int n0w = tile*128 + w*32;     // this wave's q-row base
  int lane16 = lane * 16;

  const char* kBb = kB + (size_t)b*524288;
  const char* vBb = vB + (size_t)b*524288;

  // ---- stage K0/V0 early (hidden under phase A) ----
  {
    int so = tid * 16;
#pragma unroll
    for (int r = 0; r < 4; ++r) stage16(kBb + so + r*4096, lds + so + r*4096);
#pragma unroll
    for (int r = 0; r < 4; ++r) stage16(vBb + so + r*4096, lds + 16384 + so + r*4096);
  }

  // ---- Phase A: per-wave Q build -> qf[16] B-frags (no LDS) ----
  f16x8 qf[16];
  {
    f16x8 xb[16];
    int n = n0w + l31;
    const char* xrow = xT + (size_t)(b*NPIX + n)*512;
    int n7 = n & 7;
#pragma unroll
    for (int s = 0; s < 16; ++s)
      xb[s] = *(const f16x8*)(xrow + (((2*s + hh) ^ n7) << 4));
#pragma unroll
    for (int ot = 0; ot < 8; ++ot) {
      f32x16 acc;
#pragma unroll
      for (int j = 0; j < 16; ++j) acc[j] = 0.f;
#pragma unroll
      for (int s = 0; s < 16; ++s) {
        f16x8 wa = *(const f16x8*)((const char*)WqF + (size_t)(ot*16 + s)*1024 + lane16);
        acc = mfma32(wa, xb[s], acc);    // D[o_rel][row=l31]
      }
#pragma unroll
      for (int i = 0; i < 4; ++i) {
        f32x4 bv4 = *(const f32x4*)(bq + 32*ot + 8*i + 4*hh);
#pragma unroll
        for (int j2 = 0; j2 < 4; ++j2) acc[4*i + j2] += bv4[j2];
      }
      qf[2*ot + 0] = pack_swap(acc[0], acc[1], acc[2], acc[3],
                               acc[4], acc[5], acc[6], acc[7], hh);
      qf[2*ot + 1] = pack_swap(acc[8], acc[9], acc[10], acc[11],
                               acc[12], acc[13], acc[14], acc[15], hh);
    }
  }

  // ---- main loop: 32 key-tiles, K/V double-buffer, counted vmcnt ----
  f32x16 O[8];
#pragma unroll
  for (int i = 0; i < 8; ++i)
#pragma unroll
    for (int j = 0; j < 16; ++j) O[i][j] = 0.f;
  float m_run = -3e38f, l_run = 0.f;

  for (int t = 0; t < 32; ++t) {
    char* curb = lds + ((t & 1) << 15);
    if (t < 31) {
      const char* ksrc = kBb + (size_t)(t + 1)*16384;
      const char* vsrc = vBb + (size_t)(t + 1)*16384;
      char* kd = lds + (((t + 1) & 1) << 15);
      int so = tid * 16;
#pragma unroll
      for (int r = 0; r < 4; ++r) stage16(ksrc + so + r*4096, kd + so + r*4096);
#pragma unroll
      for (int r = 0; r < 4; ++r) stage16(vsrc + so + r*4096, kd + 16384 + so + r*4096);
      WAIT_VM(8);
    } else {
      WAIT_VM(0);
    }
    S_BARRIER();

    // QK^T: S[key][row], lane owns q-row l31; reg j -> key (j&3)+8*(j>>2)+4hh
    f32x16 S16;
#pragma unroll
    for (int j = 0; j < 16; ++j) S16[j] = 0.f;
    __builtin_amdgcn_s_setprio(1);
#pragma unroll
    for (int s = 0; s < 16; ++s) {
      f16x8 kf = *(const f16x8*)(curb + s*1024 + lane16);
      S16 = mfma32(kf, qf[s], S16);
    }
    __builtin_amdgcn_s_setprio(0);

    // lane-local softmax
    float mx = S16[0];
#pragma unroll
    for (int j = 1; j < 16; ++j) mx = fmaxf(mx, S16[j]);
    mx = fmaxf(mx, __shfl_xor(mx, 32));
    if (!__all(mx <= m_run + 8.0f)) {    // T13 defer-max
      float mn = fmaxf(m_run, mx);
      float al = __expf(m_run - mn);
      m_run = mn;
      l_run *= al;
#pragma unroll
      for (int i = 0; i < 8; ++i)
#pragma unroll
        for (int j = 0; j < 16; ++j) O[i][j] *= al;
    }
    float p[16];
    float ls = 0.f;
#pragma unroll
    for (int j = 0; j < 16; ++j) { p[j] = __expf(S16[j] - m_run); ls += p[j]; }
    l_run += ls;

    // P -> f16 B-frags (shfl-based half exchange)
    f16x8 pf0 = pack_swap(p[0], p[1], p[2], p[3], p[4], p[5], p[6], p[7], hh);
    f16x8 pf1 = pack_swap(p[8], p[9], p[10], p[11], p[12], p[13], p[14], p[15], hh);

    // PV: O[c][row] += V[key][c] * P[row][key]
    __builtin_amdgcn_s_setprio(1);
#pragma unroll
    for (int ct = 0; ct < 8; ++ct) {
      f16x8 vf0 = *(const f16x8*)(curb + 16384 + (ct*2 + 0)*1024 + lane16);
      O[ct] = mfma32(vf0, pf0, O[ct]);
      f16x8 vf1 = *(const f16x8*)(curb + 16384 + (ct*2 + 1)*1024 + lane16);
      O[ct] = mfma32(vf1, pf1, O[ct]);
    }
    __builtin_amdgcn_s_setprio(0);
    S_BARRIER();
  }

  // ---- epilogue: out = gamma*O/l + x ----
  l_run += __shfl_xor(l_run, 32);
  float inv = 1.0f / l_run;
  float g = gamma_p[0];
  int n = n0w + l31;
#pragma unroll
  for (int ct = 0; ct < 8; ++ct)
#pragma unroll
    for (int j = 0; j < 16; ++j) {
      int c = 32*ct + (j & 3) + 8*(j >> 2) + 4*hh;
      size_t idx = (size_t)(b*CDIM + c)*NPIX + n;
      out[idx] = g * (O[ct][j] * inv) + xg[idx];
    }
}

extern "C" void kernel_launch(void* const* d_in, const int* in_sizes, int n_in,
                              void* d_out, int out_size, void* d_ws, size_t ws_size,
                              hipStream_t stream) {
  (void)in_sizes; (void)n_in; (void)out_size; (void)ws_size;
  const float* x     = (const float*)d_in[0];
  const float* Wq    = (const float*)d_in[1];
  const float* bq    = (const float*)d_in[2];
  const float* Wk    = (const float*)d_in[3];
  const float* bk    = (const float*)d_in[4];
  const float* Wv    = (const float*)d_in[5];
  const float* bv    = (const float*)d_in[6];
  const float* Ws    = (const float*)d_in[7];
  const float* bs    = (const float*)d_in[8];
  const float* gamma = (const float*)d_in[9];

  char* ws = (char*)d_ws;
  float* bk2 = (float*)(ws);
  float* bv2 = (float*)(ws + 1024);
  char* xT   = ws + 4096;
  char* kB   = ws + 4096 + 37748736;
  char* vB   = kB + 4194304;
  f16* WqF   = (f16*)(vB + 4194304);
  f16* Wk2H  = WqF + 65536;
  f16* Wv2H  = Wk2H + 65536;

  prep_weights<<<256, 256, 0, stream>>>(Wq, Wk, bk, Wv, bv, Ws, bs, WqF, Wk2H, Wv2H, bk2, bv2);
  transpose_x<<<dim3(8, 288, 8), dim3(32, 8), 0, stream>>>(x, xT);
  compute_kv<<<dim3(32, 8), 256, 0, stream>>>(xT, Wk2H, Wv2H, bk2, bv2, kB, vB);
  attention<<<576, 256, 0, stream>>>(xT, WqF, bq, kB, vB, x, gamma, (float*)d_out);
}